// Round 5
// baseline (1749.362 us; speedup 1.0000x reference)
//
#include <hip/hip_runtime.h>
#include <hip/hip_bf16.h>

#define Nn 20000
#define Dd 256
#define Ff 256
#define Kc 32

// k_aggr geometry
#define BK2 64
#define NSTEP2 313
#define NP2 20032           // 313*64, xpre_t column padding (zeros past 20000)

typedef __attribute__((ext_vector_type(8))) short short8;
typedef __attribute__((ext_vector_type(4))) short short4_t;
typedef __attribute__((ext_vector_type(4))) float float4_t;

static __device__ __forceinline__ short f2bf(float x) {
    union { float f; unsigned u; } v; v.f = x;
    unsigned r = v.u + 0x7FFFu + ((v.u >> 16) & 1u);   // round-to-nearest-even
    return (short)(r >> 16);
}
static __device__ __forceinline__ short4_t cvt4(float4_t v) {
    short4_t r; r[0] = f2bf(v[0]); r[1] = f2bf(v[1]); r[2] = f2bf(v[2]); r[3] = f2bf(v[3]);
    return r;
}
static __device__ __forceinline__ unsigned cvtpk(float a, float b) {
    unsigned r;
    asm("v_cvt_pk_bf16_f32 %0, %1, %2" : "=v"(r) : "v"(a), "v"(b));
    return r;   // lo = bf16(a), hi = bf16(b)  (RNE)
}
static __device__ __forceinline__ void glds16(const float* g, float* l) {
    __builtin_amdgcn_global_load_lds(
        (const __attribute__((address_space(1))) unsigned int*)g,
        (__attribute__((address_space(3))) unsigned int*)l,
        16, 0, 0);
}

// ---------------- K1: node = h @ W1  [N,32] fp32 ----------------
__global__ __launch_bounds__(256) void k_node(const float* __restrict__ h,
                                              const float* __restrict__ W1,
                                              float* __restrict__ node) {
    int t = blockIdx.x * 256 + threadIdx.x;     // N*32 threads
    int n = t >> 5, k = t & 31;
    if (n >= Nn) return;
    const float4_t* hr = (const float4_t*)(h + (size_t)n * Dd);
    float s = 0.f;
    #pragma unroll 8
    for (int d4 = 0; d4 < 64; ++d4) {
        float4_t hv = hr[d4];
        #pragma unroll
        for (int j = 0; j < 4; ++j) s += hv[j] * W1[(d4 * 4 + j) * Kc + k];
    }
    node[n * Kc + k] = s;
}

// ---------------- K1b: out = node @ b (bias pre-pass; k_aggr RMWs it) ------
__global__ __launch_bounds__(256) void k_bias(const float* __restrict__ node,
                                              const float* __restrict__ bb,
                                              float* __restrict__ out) {
    int n = blockIdx.x, f = threadIdx.x;
    const float* nr = node + (size_t)n * Kc;
    float s = 0.f;
    #pragma unroll
    for (int k = 0; k < Kc; ++k) s += nr[k] * bb[k * Ff + f];
    out[(size_t)n * Ff + f] = s;
}

// ------- K2: pack W2 (fp32 [32][256][256]) -> bf16 B-fragment order -------
__global__ __launch_bounds__(256) void k_packW2(const float* __restrict__ W2,
                                                short* __restrict__ P) {
    int t = blockIdx.x * 256 + threadIdx.x;     // 262144 threads
    int lane = t & 63;
    int cf = (t >> 6) & 15;
    int dc = (t >> 10) & 7;
    int kk = t >> 13;
    int col = cf * 16 + (lane & 15);
    int d0  = dc * 32 + (lane >> 4) * 8;
    const float* src = W2 + ((size_t)(kk * Dd + d0)) * Ff + col;
    short8 v;
    #pragma unroll
    for (int j = 0; j < 8; ++j) v[j] = f2bf(src[(size_t)j * Ff]);
    *(short8*)(P + (size_t)t * 8) = v;
}

// ---------------- K3: x_pre, stored transposed bf16 [256][NP2] ----------------
// Pad columns [Nn, NP2) are zeroed every launch (k_aggr's tail reads them).
__global__ __launch_bounds__(256, 2) void k_xpre(const float* __restrict__ h,
                                                 const float* __restrict__ node,
                                                 const short* __restrict__ P,
                                                 short* __restrict__ xpre_t) {
    __shared__ short hlds[64 * 264];        // bf16 h tile, padded stride 264
    __shared__ float ntl[32 * 64];          // node transposed [kk][n_local]
    int t = threadIdx.x;
    int n0 = blockIdx.x * 64;

    #pragma unroll
    for (int i = 0; i < 16; ++i) {
        int c = t + i * 256;                // 4096 float4 chunks
        int row = c >> 6, cc = c & 63;
        int n = n0 + row; if (n > Nn - 1) n = Nn - 1;
        float4_t v = *(const float4_t*)(h + (size_t)n * Dd + cc * 4);
        *(short4_t*)&hlds[row * 264 + cc * 4] = cvt4(v);
    }
    #pragma unroll
    for (int i = 0; i < 8; ++i) {
        int idx = t + i * 256;              // 2048
        int nl = idx >> 5, k = idx & 31;
        int n = n0 + nl; if (n > Nn - 1) n = Nn - 1;
        ntl[k * 64 + nl] = node[(size_t)n * Kc + k];
    }
    __syncthreads();

    int lane = t & 63, w = t >> 6;
    int arow = lane & 15;
    int asel = (lane >> 4) * 8;
    float4_t acc[4][4];
    #pragma unroll
    for (int a = 0; a < 4; ++a)
        #pragma unroll
        for (int b2 = 0; b2 < 4; ++b2) acc[a][b2] = (float4_t){0.f, 0.f, 0.f, 0.f};

    for (int kk = 0; kk < 32; ++kk) {
        float4_t T[4][4];
        #pragma unroll
        for (int a = 0; a < 4; ++a)
            #pragma unroll
            for (int b2 = 0; b2 < 4; ++b2) T[a][b2] = (float4_t){0.f, 0.f, 0.f, 0.f};
        #pragma unroll
        for (int dc = 0; dc < 8; ++dc) {
            short8 af[4], bfr[4];
            #pragma unroll
            for (int rf = 0; rf < 4; ++rf)
                af[rf] = *(const short8*)&hlds[(rf * 16 + arow) * 264 + dc * 32 + asel];
            #pragma unroll
            for (int cf = 0; cf < 4; ++cf)
                bfr[cf] = *(const short8*)(P + ((size_t)(((kk * 8 + dc) * 16 + w * 4 + cf) * 64 + lane)) * 8);
            #pragma unroll
            for (int rf = 0; rf < 4; ++rf)
                #pragma unroll
                for (int cf = 0; cf < 4; ++cf)
                    T[rf][cf] = __builtin_amdgcn_mfma_f32_16x16x32_bf16(af[rf], bfr[cf], T[rf][cf], 0, 0, 0);
        }
        #pragma unroll
        for (int rf = 0; rf < 4; ++rf) {
            float4_t sc = *(const float4_t*)&ntl[kk * 64 + rf * 16 + (lane >> 4) * 4];
            #pragma unroll
            for (int cf = 0; cf < 4; ++cf)
                #pragma unroll
                for (int r = 0; r < 4; ++r)
                    acc[rf][cf][r] += sc[r] * T[rf][cf][r];
        }
    }

    #pragma unroll
    for (int rf = 0; rf < 4; ++rf) {
        int nl = rf * 16 + (lane >> 4) * 4;
        #pragma unroll
        for (int cf = 0; cf < 4; ++cf) {
            int f = w * 64 + cf * 16 + (lane & 15);
            #pragma unroll
            for (int r = 0; r < 4; ++r) {
                int n = n0 + nl + r;
                if (n < Nn)      xpre_t[(size_t)f * NP2 + n] = f2bf(acc[rf][cf][r]);
                else if (n < NP2) xpre_t[(size_t)f * NP2 + n] = 0;
            }
        }
    }
}

// ---------------- K4: out = relu(adj @ x_pre + out) ----------------
// BM=64 (313 blocks), BN=256, BK=64, 512 threads (8 waves = 2M x 4N).
// adj staged fp32 via global_load_lds (2-deep, counted vmcnt(2), raw
// s_barrier). LDS = 32.8 KB -> 2 blocks/CU for cross-block latency hiding.
// XOR swizzle (row&7)<<2 on source + read (rule #21). Bias pre-added by k_bias.
__global__ __launch_bounds__(512, 4) void k_aggr(const float* __restrict__ adj,
                                                 const short* __restrict__ xpre_t,
                                                 float* __restrict__ out) {
    __shared__ float alds[2][4096];         // 2 x 16.4 KB, [64 rows][64 cols]

    const int t = threadIdx.x;
    const int lane = t & 63, w = t >> 6;
    const int wm = w >> 2, wn = w & 3;      // 2M x 4N wave grid
    const int m0 = blockIdx.x * 64;

    // glds source geometry: 2 issues/wave, chunk = w*2+i covers rows [4c,4c+4)
    long rowbase[2]; int colp[2];
    #pragma unroll
    for (int i = 0; i < 2; ++i) {
        int d = (w * 2 + i) * 256 + lane * 4;   // linear dest float idx
        int row = d >> 6, col = d & 63;
        int r = m0 + row; if (r > Nn - 1) r = Nn - 1;
        rowbase[i] = (long)r * Nn;
        colp[i] = col ^ ((row & 7) << 2);       // pre-swizzled source col
    }
    // B fragment pointers (xpre_t[f][n], zero-padded cols >= Nn)
    const short* bp0 = xpre_t + (long)(wn * 64 +  0 + (lane & 15)) * NP2 + (lane >> 4) * 8;
    const short* bp1 = xpre_t + (long)(wn * 64 + 16 + (lane & 15)) * NP2 + (lane >> 4) * 8;
    const short* bp2 = xpre_t + (long)(wn * 64 + 32 + (lane & 15)) * NP2 + (lane >> 4) * 8;
    const short* bp3 = xpre_t + (long)(wn * 64 + 48 + (lane & 15)) * NP2 + (lane >> 4) * 8;

    float4_t acc[2][4];
    #pragma unroll
    for (int rf = 0; rf < 2; ++rf)
        #pragma unroll
        for (int cf = 0; cf < 4; ++cf) acc[rf][cf] = (float4_t){0.f, 0.f, 0.f, 0.f};

    short8 Bf[2][4];

    // prologue: A(0) -> buf0
    #pragma unroll
    for (int i = 0; i < 2; ++i)
        glds16(adj + rowbase[i] + colp[i], &alds[0][(w * 2 + i) * 256]);

    #pragma unroll 1
    for (int s = 0; s < NSTEP2; ++s) {
        const int cur = s & 1;
        // B(s): 8x16B from L2/L3 (issued BEFORE glds so vmcnt(2) covers them)
        const long so = (long)s * BK2;
        #pragma unroll
        for (int dc = 0; dc < 2; ++dc) {
            Bf[dc][0] = *(const short8*)(bp0 + so + dc * 32);
            Bf[dc][1] = *(const short8*)(bp1 + so + dc * 32);
            Bf[dc][2] = *(const short8*)(bp2 + so + dc * 32);
            Bf[dc][3] = *(const short8*)(bp3 + so + dc * 32);
        }
        __builtin_amdgcn_sched_barrier(0);
        if (s + 1 < NSTEP2) {
            #pragma unroll
            for (int i = 0; i < 2; ++i) {
                int c = (s + 1) * BK2 + colp[i];
                if (c > Nn - 4) c = Nn - 4;     // tail clamp; xpre pad zeros kill it
                glds16(adj + rowbase[i] + c, &alds[cur ^ 1][(w * 2 + i) * 256]);
            }
            __builtin_amdgcn_sched_barrier(0);
            asm volatile("s_waitcnt vmcnt(2)" ::: "memory");   // A(s)+B done; A(s+1) flies
        } else {
            __builtin_amdgcn_sched_barrier(0);
            asm volatile("s_waitcnt vmcnt(0)" ::: "memory");
        }
        __builtin_amdgcn_s_barrier();
        __builtin_amdgcn_sched_barrier(0);

        const float* ab = alds[cur];
        #pragma unroll
        for (int dc = 0; dc < 2; ++dc) {
            #pragma unroll
            for (int rf = 0; rf < 2; ++rf) {
                const int rl = wm * 32 + rf * 16 + (lane & 15);
                const int sw = (rl & 7) << 2;
                const int c0 = dc * 32 + (lane >> 4) * 8;
                float4_t lo = *(const float4_t*)&ab[rl * 64 + ((c0    ) ^ sw)];
                float4_t hi = *(const float4_t*)&ab[rl * 64 + ((c0 + 4) ^ sw)];
                union { short8 s8; unsigned u[4]; } af;
                af.u[0] = cvtpk(lo[0], lo[1]); af.u[1] = cvtpk(lo[2], lo[3]);
                af.u[2] = cvtpk(hi[0], hi[1]); af.u[3] = cvtpk(hi[2], hi[3]);
                #pragma unroll
                for (int cf = 0; cf < 4; ++cf)
                    acc[rf][cf] = __builtin_amdgcn_mfma_f32_16x16x32_bf16(af.s8, Bf[dc][cf], acc[rf][cf], 0, 0, 0);
            }
        }
        __builtin_amdgcn_s_barrier();       // protect alds[cur] before A(s+2) writes
    }

    // epilogue: RMW bias (pre-written by k_bias), relu, store
    #pragma unroll
    for (int rf = 0; rf < 2; ++rf) {
        #pragma unroll
        for (int cf = 0; cf < 4; ++cf) {
            const int fl = wn * 64 + cf * 16 + (lane & 15);
            #pragma unroll
            for (int q = 0; q < 4; ++q) {
                int n = m0 + wm * 32 + rf * 16 + (lane >> 4) * 4 + q;
                if (n < Nn) {
                    float* op = out + (size_t)n * Ff + fl;
                    float v = acc[rf][cf][q] + *op;
                    *op = v > 0.f ? v : 0.f;
                }
            }
        }
    }
}

extern "C" void kernel_launch(void* const* d_in, const int* in_sizes, int n_in,
                              void* d_out, int out_size, void* d_ws, size_t ws_size,
                              hipStream_t stream) {
    const float* h   = (const float*)d_in[0];
    const float* adj = (const float*)d_in[1];
    const float* W1  = (const float*)d_in[2];
    const float* W2  = (const float*)d_in[3];
    const float* b   = (const float*)d_in[4];
    float* out = (float*)d_out;

    char* ws = (char*)d_ws;
    float* node   = (float*)ws;                               // 2,560,000 B
    short* P      = (short*)(ws + 2560000);                   // 4,194,304 B
    short* xpre_t = (short*)(ws + 2560000 + 4194304);         // 10,256,384 B (256 x 20032)

    k_node  <<<2500,  256, 0, stream>>>(h, W1, node);
    k_bias  <<<Nn,    256, 0, stream>>>(node, b, out);
    k_packW2<<<1024,  256, 0, stream>>>(W2, P);
    k_xpre  <<<313,   256, 0, stream>>>(h, node, P, xpre_t);
    k_aggr  <<<313,   512, 0, stream>>>(adj, xpre_t, out);
}

// Round 6
// 1014.149 us; speedup vs baseline: 1.7250x; 1.7250x over previous
//
#include <hip/hip_runtime.h>
#include <hip/hip_bf16.h>

#define Nn 20000
#define Dd 256
#define Ff 256
#define Kc 32
#define NP2 20096           // xpre_t padded cols (zeros past 20000)

typedef __attribute__((ext_vector_type(8))) short short8;
typedef __attribute__((ext_vector_type(4))) short short4_t;
typedef __attribute__((ext_vector_type(4))) float float4_t;

static __device__ __forceinline__ short f2bf(float x) {
    union { float f; unsigned u; } v; v.f = x;
    unsigned r = v.u + 0x7FFFu + ((v.u >> 16) & 1u);   // round-to-nearest-even
    return (short)(r >> 16);
}
static __device__ __forceinline__ short4_t cvt4(float4_t v) {
    short4_t r; r[0] = f2bf(v[0]); r[1] = f2bf(v[1]); r[2] = f2bf(v[2]); r[3] = f2bf(v[3]);
    return r;
}
static __device__ __forceinline__ unsigned cvtpk(float a, float b) {
    unsigned r;
    asm("v_cvt_pk_bf16_f32 %0, %1, %2" : "=v"(r) : "v"(a), "v"(b));
    return r;   // lo = bf16(a), hi = bf16(b)  (RNE)
}
static __device__ __forceinline__ void glds16(const float* g, float* l) {
    __builtin_amdgcn_global_load_lds(
        (const __attribute__((address_space(1))) unsigned int*)g,
        (__attribute__((address_space(3))) unsigned int*)l,
        16, 0, 0);
}

// ---------------- K1: node = h @ W1  [N,32] fp32 ----------------
__global__ __launch_bounds__(256) void k_node(const float* __restrict__ h,
                                              const float* __restrict__ W1,
                                              float* __restrict__ node) {
    int t = blockIdx.x * 256 + threadIdx.x;
    int n = t >> 5, k = t & 31;
    if (n >= Nn) return;
    const float4_t* hr = (const float4_t*)(h + (size_t)n * Dd);
    float s = 0.f;
    #pragma unroll 8
    for (int d4 = 0; d4 < 64; ++d4) {
        float4_t hv = hr[d4];
        #pragma unroll
        for (int j = 0; j < 4; ++j) s += hv[j] * W1[(d4 * 4 + j) * Kc + k];
    }
    node[n * Kc + k] = s;
}

// ---------------- K1b: out = node @ b (bias pre-pass; k_aggr atomicAdds) ---
__global__ __launch_bounds__(256) void k_bias(const float* __restrict__ node,
                                              const float* __restrict__ bb,
                                              float* __restrict__ out) {
    int n = blockIdx.x, f = threadIdx.x;
    const float* nr = node + (size_t)n * Kc;
    float s = 0.f;
    #pragma unroll
    for (int k = 0; k < Kc; ++k) s += nr[k] * bb[k * Ff + f];
    out[(size_t)n * Ff + f] = s;
}

// ------- K2: pack W2 (fp32 [32][256][256]) -> bf16 B-fragment order -------
__global__ __launch_bounds__(256) void k_packW2(const float* __restrict__ W2,
                                                short* __restrict__ P) {
    int t = blockIdx.x * 256 + threadIdx.x;
    int lane = t & 63;
    int cf = (t >> 6) & 15;
    int dc = (t >> 10) & 7;
    int kk = t >> 13;
    int col = cf * 16 + (lane & 15);
    int d0  = dc * 32 + (lane >> 4) * 8;
    const float* src = W2 + ((size_t)(kk * Dd + d0)) * Ff + col;
    short8 v;
    #pragma unroll
    for (int j = 0; j < 8; ++j) v[j] = f2bf(src[(size_t)j * Ff]);
    *(short8*)(P + (size_t)t * 8) = v;
}

// ---------------- K3: x_pre, stored transposed bf16 [256][NP2] ----------------
__global__ __launch_bounds__(256, 2) void k_xpre(const float* __restrict__ h,
                                                 const float* __restrict__ node,
                                                 const short* __restrict__ P,
                                                 short* __restrict__ xpre_t) {
    __shared__ short hlds[64 * 264];
    __shared__ float ntl[32 * 64];
    int t = threadIdx.x;
    int n0 = blockIdx.x * 64;

    #pragma unroll
    for (int i = 0; i < 16; ++i) {
        int c = t + i * 256;
        int row = c >> 6, cc = c & 63;
        int n = n0 + row; if (n > Nn - 1) n = Nn - 1;
        float4_t v = *(const float4_t*)(h + (size_t)n * Dd + cc * 4);
        *(short4_t*)&hlds[row * 264 + cc * 4] = cvt4(v);
    }
    #pragma unroll
    for (int i = 0; i < 8; ++i) {
        int idx = t + i * 256;
        int nl = idx >> 5, k = idx & 31;
        int n = n0 + nl; if (n > Nn - 1) n = Nn - 1;
        ntl[k * 64 + nl] = node[(size_t)n * Kc + k];
    }
    __syncthreads();

    int lane = t & 63, w = t >> 6;
    int arow = lane & 15;
    int asel = (lane >> 4) * 8;
    float4_t acc[4][4];
    #pragma unroll
    for (int a = 0; a < 4; ++a)
        #pragma unroll
        for (int b2 = 0; b2 < 4; ++b2) acc[a][b2] = (float4_t){0.f, 0.f, 0.f, 0.f};

    for (int kk = 0; kk < 32; ++kk) {
        float4_t T[4][4];
        #pragma unroll
        for (int a = 0; a < 4; ++a)
            #pragma unroll
            for (int b2 = 0; b2 < 4; ++b2) T[a][b2] = (float4_t){0.f, 0.f, 0.f, 0.f};
        #pragma unroll
        for (int dc = 0; dc < 8; ++dc) {
            short8 af[4], bfr[4];
            #pragma unroll
            for (int rf = 0; rf < 4; ++rf)
                af[rf] = *(const short8*)&hlds[(rf * 16 + arow) * 264 + dc * 32 + asel];
            #pragma unroll
            for (int cf = 0; cf < 4; ++cf)
                bfr[cf] = *(const short8*)(P + ((size_t)(((kk * 8 + dc) * 16 + w * 4 + cf) * 64 + lane)) * 8);
            #pragma unroll
            for (int rf = 0; rf < 4; ++rf)
                #pragma unroll
                for (int cf = 0; cf < 4; ++cf)
                    T[rf][cf] = __builtin_amdgcn_mfma_f32_16x16x32_bf16(af[rf], bfr[cf], T[rf][cf], 0, 0, 0);
        }
        #pragma unroll
        for (int rf = 0; rf < 4; ++rf) {
            float4_t sc = *(const float4_t*)&ntl[kk * 64 + rf * 16 + (lane >> 4) * 4];
            #pragma unroll
            for (int cf = 0; cf < 4; ++cf)
                #pragma unroll
                for (int r = 0; r < 4; ++r)
                    acc[rf][cf][r] += sc[r] * T[rf][cf][r];
        }
    }

    #pragma unroll
    for (int rf = 0; rf < 4; ++rf) {
        int nl = rf * 16 + (lane >> 4) * 4;
        #pragma unroll
        for (int cf = 0; cf < 4; ++cf) {
            int f = w * 64 + cf * 16 + (lane & 15);
            #pragma unroll
            for (int r = 0; r < 4; ++r) {
                int n = n0 + nl + r;
                if (n < Nn)       xpre_t[(size_t)f * NP2 + n] = f2bf(acc[rf][cf][r]);
                else if (n < NP2) xpre_t[(size_t)f * NP2 + n] = 0;
            }
        }
    }
}

// ---------------- K4: out += adj @ x_pre (atomic, K-split x2) ----------------
// BM=64, BK=64, 512 threads (8 waves, each: all 64 rows x 32 cols).
// A: glds 2 steps ahead, 3 LDS buffers, 1 raw barrier/step, uniform vmcnt(6).
// B: register double-buffer, 1 step ahead (statically indexed, x2 unroll).
// grid 626 = 2 k-splits x 313 row-tiles; LDS 48KB + VGPR<=128 -> 2 blocks/CU.
__global__ __launch_bounds__(512, 4) void k_aggr(const float* __restrict__ adj,
                                                 const short* __restrict__ xpre_t,
                                                 float* __restrict__ out) {
    __shared__ float lds0[4096], lds1[4096], lds2[4096];

    const int t = threadIdx.x;
    const int lane = t & 63, w = t >> 6;
    const int bid = blockIdx.x;
    const int split = bid >= 313;
    const int m0 = (split ? bid - 313 : bid) * 64;
    const int k0 = split ? 9984 : 0;      // boundary multiple of BK=64
    const int ns = split ? 157 : 156;     // split1 tail covered by xpre zero-pad

    // glds source geometry: 2 issues/wave, linear LDS dest, XOR-swizzled source
    long rowbase[2]; int colp[2];
    #pragma unroll
    for (int i = 0; i < 2; ++i) {
        int d = (w * 2 + i) * 256 + lane * 4;   // linear LDS float idx
        int row = d >> 6, col = d & 63;
        int r = m0 + row; if (r > Nn - 1) r = Nn - 1;
        rowbase[i] = (long)r * Nn;
        colp[i] = col ^ ((row & 7) << 2);
    }
    // B fragment pointers: wave w owns f-cols [w*32, w*32+32)
    const short* bp0 = xpre_t + (long)(w * 32 + (lane & 15)) * NP2 + k0 + (lane >> 4) * 8;
    const short* bp1 = bp0 + 16L * NP2;

    float4_t acc[4][2];
    #pragma unroll
    for (int rf = 0; rf < 4; ++rf) {
        acc[rf][0] = (float4_t){0.f, 0.f, 0.f, 0.f};
        acc[rf][1] = (float4_t){0.f, 0.f, 0.f, 0.f};
    }
    short8 B0[2][2], B1[2][2];

    float* pR = lds0; float* pM = lds1; float* pW = lds2;
    int s = 0;

#define LOADB(Bn_, off_) do { _Pragma("unroll") for (int dc = 0; dc < 2; ++dc) { \
        Bn_[dc][0] = *(const short8*)(bp0 + (off_) + dc * 32); \
        Bn_[dc][1] = *(const short8*)(bp1 + (off_) + dc * 32); } } while (0)

// FIFO per step: LOADB(4) ... vmcnt(6) keeps [A(s+1)x2, B(s+1)x4], drains
// A(s), B(s). glds A(s+2) issued AFTER compute (end of step) -> 2-deep.
#define STEP(Bc_, Bn_) do { \
        LOADB(Bn_, (long)(s + 1) * 64); \
        asm volatile("s_waitcnt vmcnt(6) lgkmcnt(0)" ::: "memory"); \
        __builtin_amdgcn_s_barrier(); \
        __builtin_amdgcn_sched_barrier(0); \
        _Pragma("unroll") for (int dc = 0; dc < 2; ++dc) { \
            _Pragma("unroll") for (int rf = 0; rf < 4; ++rf) { \
                const int rl = rf * 16 + (lane & 15); \
                const int sw = (rl & 7) << 2; \
                const int c0 = dc * 32 + (lane >> 4) * 8; \
                float4_t lo = *(const float4_t*)&pR[rl * 64 + ((c0    ) ^ sw)]; \
                float4_t hi = *(const float4_t*)&pR[rl * 64 + ((c0 + 4) ^ sw)]; \
                union { short8 s8; unsigned u[4]; } af; \
                af.u[0] = cvtpk(lo[0], lo[1]); af.u[1] = cvtpk(lo[2], lo[3]); \
                af.u[2] = cvtpk(hi[0], hi[1]); af.u[3] = cvtpk(hi[2], hi[3]); \
                acc[rf][0] = __builtin_amdgcn_mfma_f32_16x16x32_bf16(af.s8, Bc_[dc][0], acc[rf][0], 0, 0, 0); \
                acc[rf][1] = __builtin_amdgcn_mfma_f32_16x16x32_bf16(af.s8, Bc_[dc][1], acc[rf][1], 0, 0, 0); } } \
        { int gc0 = k0 + (s + 2) * 64 + colp[0]; if (gc0 > Nn - 4) gc0 = Nn - 4; \
          int gc1 = k0 + (s + 2) * 64 + colp[1]; if (gc1 > Nn - 4) gc1 = Nn - 4; \
          glds16(adj + rowbase[0] + gc0, pW + (w * 2 + 0) * 256); \
          glds16(adj + rowbase[1] + gc1, pW + (w * 2 + 1) * 256); } \
        { float* tp_ = pR; pR = pM; pM = pW; pW = tp_; } \
        ++s; } while (0)

    // prologue (FIFO: A(0)x2, B(0)x4, A(1)x2)
    glds16(adj + rowbase[0] + k0 + colp[0], pR + (w * 2 + 0) * 256);
    glds16(adj + rowbase[1] + k0 + colp[1], pR + (w * 2 + 1) * 256);
    asm volatile("" ::: "memory");
    LOADB(B0, 0L);
    asm volatile("" ::: "memory");
    glds16(adj + rowbase[0] + k0 + 64 + colp[0], pM + (w * 2 + 0) * 256);
    glds16(adj + rowbase[1] + k0 + 64 + colp[1], pM + (w * 2 + 1) * 256);
    asm volatile("" ::: "memory");

    #pragma unroll 1
    for (int p = 0; p < (ns >> 1); ++p) {
        STEP(B0, B1);
        STEP(B1, B0);
    }
    if (ns & 1) STEP(B0, B1);

    // epilogue: atomic accumulate onto bias-initialized out
    #pragma unroll
    for (int rf = 0; rf < 4; ++rf) {
        #pragma unroll
        for (int cf = 0; cf < 2; ++cf) {
            const int fl = w * 32 + cf * 16 + (lane & 15);
            #pragma unroll
            for (int q = 0; q < 4; ++q) {
                int n = m0 + rf * 16 + (lane >> 4) * 4 + q;
                if (n < Nn) atomicAdd(out + (size_t)n * Ff + fl, acc[rf][cf][q]);
            }
        }
    }
#undef LOADB
#undef STEP
}

// ---------------- K5: out = relu(out) ----------------
__global__ __launch_bounds__(256) void k_final(float* __restrict__ out) {
    int i = blockIdx.x * 256 + threadIdx.x;     // 640000 threads, 2 float4 each
    float4_t* o = (float4_t*)out;
    #pragma unroll
    for (int j = 0; j < 2; ++j) {
        int idx = i + j * 640000;
        float4_t v = o[idx];
        #pragma unroll
        for (int q = 0; q < 4; ++q) v[q] = v[q] > 0.f ? v[q] : 0.f;
        o[idx] = v;
    }
}

extern "C" void kernel_launch(void* const* d_in, const int* in_sizes, int n_in,
                              void* d_out, int out_size, void* d_ws, size_t ws_size,
                              hipStream_t stream) {
    const float* h   = (const float*)d_in[0];
    const float* adj = (const float*)d_in[1];
    const float* W1  = (const float*)d_in[2];
    const float* W2  = (const float*)d_in[3];
    const float* b   = (const float*)d_in[4];
    float* out = (float*)d_out;

    char* ws = (char*)d_ws;
    float* node   = (float*)ws;                               // 2,560,000 B
    short* P      = (short*)(ws + 2560000);                   // 4,194,304 B
    short* xpre_t = (short*)(ws + 2560000 + 4194304);         // 10,289,152 B (256 x 20096)

    k_node  <<<2500, 256, 0, stream>>>(h, W1, node);
    k_bias  <<<Nn,   256, 0, stream>>>(node, b, out);
    k_packW2<<<1024, 256, 0, stream>>>(W2, P);
    k_xpre  <<<314,  256, 0, stream>>>(h, node, P, xpre_t);
    k_aggr  <<<626,  512, 0, stream>>>(adj, xpre_t, out);
    k_final <<<2500, 256, 0, stream>>>(out);
}